// Round 4
// baseline (606.708 us; speedup 1.0000x reference)
//
#include <hip/hip_runtime.h>

// ARMA GCN (K=2, two layers) on MI355X.
//   Layer1: h = mean_k relu( A@(x@iw1_k) + x@rw1_k + b1_k )   [N,16]
//   Layer2: out = mean_k relu( (A@h)@iw2_k + h@rw2_k + b2_k ) [N,40]
// - Aggregation commutes with right-multiplies: propagate 32-wide H1, 16-wide h.
// - dinv folded symmetrically: Hs = dinv*H1 (bf16), pull sums then *dinv[n].
// - CSR build: coarse radix by dst>>9 (4B packed entries), then per-bucket
//   histogram/scan (k_hist, 196 blocks) + parallel scatter (k_scat, 196x8
//   blocks, global node cursors; writes land in XCD-local <=128KB windows).
// - Props: block stages its contiguous CSR src-segment in LDS, 4x-unrolled
//   gathers (4 independent dwordx4 in flight per lane).
// - GEMM1 via bf16 MFMA 3-term hi/lo split (~fp32 accuracy), LDS/barrier-free.

#define TB 256
#define CHA 4096   // edges per block in count/binA passes
#define SCAP 4096  // LDS-staged srcs capacity per prop block (64 nodes)

typedef __attribute__((ext_vector_type(8))) short bf8;
typedef __attribute__((ext_vector_type(4))) float f4;

__device__ inline unsigned short f2bf_rne(float f) {
  unsigned int u = __float_as_uint(f);
  unsigned int r = u + 0x7fffu + ((u >> 16) & 1u);
  return (unsigned short)(r >> 16);
}
__device__ inline float bf2f(unsigned short h) {
  return __uint_as_float(((unsigned int)h) << 16);
}
__device__ inline float bflo(unsigned int u) { return __uint_as_float(u << 16); }
__device__ inline float bfhi(unsigned int u) { return __uint_as_float(u & 0xffff0000u); }
__device__ inline unsigned int bfpack(float lo, float hi) {
  return (unsigned int)f2bf_rne(lo) | ((unsigned int)f2bf_rne(hi) << 16);
}
__device__ inline void acc8(float* a, uint4 v) {
  a[0] += bflo(v.x); a[1] += bfhi(v.x);
  a[2] += bflo(v.y); a[3] += bfhi(v.y);
  a[4] += bflo(v.z); a[5] += bfhi(v.z);
  a[6] += bflo(v.w); a[7] += bfhi(v.w);
}
__device__ inline void acc4(float* a, uint2 v) {
  a[0] += bflo(v.x); a[1] += bfhi(v.x);
  a[2] += bflo(v.y); a[3] += bfhi(v.y);
}

// ---------------- pass 0: coarse histogram (bucket = dst>>9) ----------------
__global__ __launch_bounds__(TB) void k_countA(const int* __restrict__ dst,
                                               int* __restrict__ ccnt, int E) {
  __shared__ int cnt[256];
  int tid = threadIdx.x;
  cnt[tid] = 0;
  __syncthreads();
  int e0 = blockIdx.x * CHA;
  int e1 = min(e0 + CHA, E);
  for (int e = e0 + tid; e < e1; e += TB) atomicAdd(&cnt[dst[e] >> 9], 1);
  __syncthreads();
  if (cnt[tid] > 0) atomicAdd(&ccnt[tid], cnt[tid]);
}

// ---------------- pass 0b: scan 256 coarse counts ----------------
__global__ __launch_bounds__(256) void k_scanC(const int* __restrict__ ccnt,
                                               int* __restrict__ cbase,
                                               int* __restrict__ ccur) {
  __shared__ int sh[256];
  int tid = threadIdx.x;
  int v = ccnt[tid];
  sh[tid] = v;
  __syncthreads();
  for (int d = 1; d < 256; d <<= 1) {
    int t = (tid >= d) ? sh[tid - d] : 0;
    __syncthreads();
    sh[tid] += t;
    __syncthreads();
  }
  int excl = sh[tid] - v;
  cbase[tid] = excl;
  ccur[tid] = excl;
  if (tid == 255) cbase[256] = sh[255];  // total = E
}

// ---------------- pass 1: partition packed edges into coarse buckets --------
// epack entry: (dst&511)<<23 | src   (src < 2^23)
__global__ __launch_bounds__(TB) void k_binA(const int* __restrict__ src,
                                             const int* __restrict__ dst,
                                             int* __restrict__ ccur,
                                             unsigned int* __restrict__ epack, int E) {
  __shared__ int cnt[256];
  __shared__ int gb[256];
  int tid = threadIdx.x;
  cnt[tid] = 0;
  __syncthreads();
  int e0 = blockIdx.x * CHA;
  int e1 = min(e0 + CHA, E);
  for (int e = e0 + tid; e < e1; e += TB) atomicAdd(&cnt[dst[e] >> 9], 1);
  __syncthreads();
  int c = cnt[tid];
  if (c > 0) gb[tid] = atomicAdd(&ccur[tid], c);
  __syncthreads();
  cnt[tid] = 0;
  __syncthreads();
  for (int e = e0 + tid; e < e1; e += TB) {
    int dv = dst[e];
    int b = dv >> 9;
    int r = atomicAdd(&cnt[b], 1);
    epack[gb[b] + r] = ((unsigned int)(dv & 511) << 23) | (unsigned int)src[e];
  }
}

// ---------------- pass 2a: per-bucket histogram+scan -> degi/offsets/cursor/dinv
__global__ __launch_bounds__(TB) void k_hist(const unsigned int* __restrict__ epack,
                                             const int* __restrict__ cbase,
                                             int* __restrict__ degi,
                                             int* __restrict__ offsets,
                                             int* __restrict__ cursor,
                                             float* __restrict__ dinv, int N) {
  __shared__ int cnt[512];
  __shared__ int pre[512];
  int b = blockIdx.x;
  int n0 = b << 9;
  int tid = threadIdx.x;
  int beg = cbase[b], end = cbase[b + 1];
  int i0 = tid, i1 = tid + 256;
  cnt[i0] = 0; cnt[i1] = 0;
  __syncthreads();
  for (int e = beg + tid; e < end; e += TB) atomicAdd(&cnt[epack[e] >> 23], 1);
  __syncthreads();
  pre[i0] = cnt[i0]; pre[i1] = cnt[i1];
  __syncthreads();
  for (int d = 1; d < 512; d <<= 1) {
    int t0 = (i0 >= d) ? pre[i0 - d] : 0;
    int t1 = (i1 >= d) ? pre[i1 - d] : 0;
    __syncthreads();
    pre[i0] += t0; pre[i1] += t1;
    __syncthreads();
  }
  int e0 = pre[i0] - cnt[i0];
  int e1x = pre[i1] - cnt[i1];
  if (n0 + i0 < N) {
    int c = cnt[i0];
    degi[n0 + i0] = c; offsets[n0 + i0] = beg + e0; cursor[n0 + i0] = beg + e0;
    dinv[n0 + i0] = c > 0 ? rsqrtf((float)c) : 0.f;
  }
  if (n0 + i1 < N) {
    int c = cnt[i1];
    degi[n0 + i1] = c; offsets[n0 + i1] = beg + e1x; cursor[n0 + i1] = beg + e1x;
    dinv[n0 + i1] = c > 0 ? rsqrtf((float)c) : 0.f;
  }
}

// ---------------- pass 2b: parallel scatter of srcs (gridDim.y chunks/bucket)
__global__ __launch_bounds__(TB) void k_scat(const unsigned int* __restrict__ epack,
                                             const int* __restrict__ cbase,
                                             int* __restrict__ cursor,
                                             int* __restrict__ srcs) {
  int b = blockIdx.x;
  int beg = cbase[b], end = cbase[b + 1];
  int len = end - beg;
  int ny = (int)gridDim.y;
  int chunk = (len + ny - 1) / ny;
  int lo = beg + blockIdx.y * chunk;
  int hi = min(lo + chunk, end);
  for (int e = lo + (int)threadIdx.x; e < hi; e += TB) {
    unsigned int v = epack[e];
    int node = (b << 9) + (int)(v >> 23);
    int pos = atomicAdd(&cursor[node], 1);
    srcs[pos] = (int)(v & 0x7FFFFFu);
  }
}

// ---------------- weight split: fragment-ordered hi/lo bf16 tables ----------
__global__ __launch_bounds__(TB) void k_wsplit(const float* __restrict__ iw1,
                                               const float* __restrict__ rw1,
                                               short* __restrict__ Whi,
                                               short* __restrict__ Wlo) {
  int idx = blockIdx.x * TB + threadIdx.x;
  if (idx >= 32768) return;
  int j = idx & 7;
  int l = (idx >> 3) & 63;
  int t = (idx >> 9) & 3;
  int c = idx >> 11;
  int k = c * 32 + (l >> 4) * 8 + j;
  int n = t * 16 + (l & 15);
  float w;
  if (n < 16)
    w = iw1[k * 16 + n];
  else if (n < 32)
    w = iw1[8192 + k * 16 + (n - 16)];
  else if (n < 48)
    w = rw1[k * 16 + (n - 32)];
  else
    w = rw1[8192 + k * 16 + (n - 48)];
  unsigned short h = f2bf_rne(w);
  float res = w - bf2f(h);
  Whi[idx] = (short)h;
  Wlo[idx] = (short)f2bf_rne(res);
}

// ---------------- GEMM1 via MFMA ----------------
// Hs[N,32] bf16 = dinv[n] * x@[iw1_0|iw1_1];  R[N,32] fp32 = x@[rw1_0|rw1_1].
__global__ __launch_bounds__(TB) void k_gemm1_mfma(const float* __restrict__ x,
                                                   const short* __restrict__ Whi,
                                                   const short* __restrict__ Wlo,
                                                   const float* __restrict__ dinv,
                                                   unsigned short* __restrict__ Hs,
                                                   float* __restrict__ R, int N) {
  int lane = threadIdx.x & 63;
  int wave = threadIdx.x >> 6;
  int row0 = blockIdx.x * 64 + wave * 16;
  int m = lane & 15, quad = lane >> 4;
  int r = row0 + m;
  bool rv = (r < N);
  const float* xr = x + (size_t)r * 512;

  f4 acc[4];
#pragma unroll
  for (int t = 0; t < 4; t++) acc[t] = (f4){0.f, 0.f, 0.f, 0.f};

  for (int c = 0; c < 16; ++c) {
    float xv[8];
    if (rv) {
      f4 a0 = *(const f4*)(xr + c * 32 + quad * 8);
      f4 a1 = *(const f4*)(xr + c * 32 + quad * 8 + 4);
      xv[0] = a0.x; xv[1] = a0.y; xv[2] = a0.z; xv[3] = a0.w;
      xv[4] = a1.x; xv[5] = a1.y; xv[6] = a1.z; xv[7] = a1.w;
    } else {
#pragma unroll
      for (int j = 0; j < 8; ++j) xv[j] = 0.f;
    }
    bf8 ahi, alo;
#pragma unroll
    for (int j = 0; j < 8; ++j) {
      unsigned short h = f2bf_rne(xv[j]);
      float res = xv[j] - bf2f(h);
      ahi[j] = (short)h;
      alo[j] = (short)f2bf_rne(res);
    }
    const short* wb = Whi + ((size_t)(c * 4) * 64 + lane) * 8;
    const short* wl = Wlo + ((size_t)(c * 4) * 64 + lane) * 8;
#pragma unroll
    for (int t = 0; t < 4; ++t) {
      bf8 bh = *(const bf8*)(wb + t * 512);
      bf8 bl = *(const bf8*)(wl + t * 512);
      acc[t] = __builtin_amdgcn_mfma_f32_16x16x32_bf16(ahi, bh, acc[t], 0, 0, 0);
      acc[t] = __builtin_amdgcn_mfma_f32_16x16x32_bf16(alo, bh, acc[t], 0, 0, 0);
      acc[t] = __builtin_amdgcn_mfma_f32_16x16x32_bf16(ahi, bl, acc[t], 0, 0, 0);
    }
  }
  float dv[4];
#pragma unroll
  for (int g = 0; g < 4; ++g) {
    int ro = row0 + quad * 4 + g;
    dv[g] = (ro < N) ? dinv[ro] : 0.f;
  }
#pragma unroll
  for (int t = 0; t < 4; ++t) {
#pragma unroll
    for (int g = 0; g < 4; ++g) {
      int ro = row0 + quad * 4 + g;
      if (ro < N) {
        if (t < 2)
          Hs[(size_t)ro * 32 + t * 16 + m] = f2bf_rne(acc[t][g] * dv[g]);
        else
          R[(size_t)ro * 32 + (t - 2) * 16 + m] = acc[t][g];
      }
    }
  }
}

// ---------------- prop1: h = mean_k relu(dinv[n]*sum Hs[src] + R + b1) -------
// Block = 64 nodes, 4 lanes/node. CSR src segment staged in LDS; 4x unroll.
__global__ __launch_bounds__(TB) void k_prop1(const int* __restrict__ offsets,
                                              const int* __restrict__ degi,
                                              const int* __restrict__ srcs,
                                              const unsigned short* __restrict__ Hs,
                                              const float* __restrict__ R,
                                              const float* __restrict__ dinv,
                                              const float* __restrict__ b1,
                                              float* __restrict__ h,
                                              unsigned short* __restrict__ hs,
                                              int N, int E) {
  __shared__ int sh[SCAP];
  int n0 = blockIdx.x * 64;
  int tid = threadIdx.x;
  int q = tid & 3;
  int n = n0 + (tid >> 2);
  int beg0 = offsets[n0];
  int end0 = (n0 + 64 < N) ? offsets[n0 + 64] : E;
  int seg = end0 - beg0;
  bool lds_ok = (seg <= SCAP);
  if (lds_ok) {
    for (int i = tid; i < seg; i += TB) sh[i] = srcs[beg0 + i];
  }
  __syncthreads();
  if (n >= N) return;
  int beg = offsets[n], cnt = degi[n];
  const unsigned short* Hsq = Hs + q * 8;
  float a[8] = {0.f, 0.f, 0.f, 0.f, 0.f, 0.f, 0.f, 0.f};
  int i = 0;
  if (lds_ok) {
    int ib = beg - beg0;
    for (; i + 4 <= cnt; i += 4) {
      int s0 = sh[ib + i], s1 = sh[ib + i + 1], s2 = sh[ib + i + 2], s3 = sh[ib + i + 3];
      uint4 v0 = *(const uint4*)(Hsq + (size_t)s0 * 32);
      uint4 v1 = *(const uint4*)(Hsq + (size_t)s1 * 32);
      uint4 v2 = *(const uint4*)(Hsq + (size_t)s2 * 32);
      uint4 v3 = *(const uint4*)(Hsq + (size_t)s3 * 32);
      acc8(a, v0); acc8(a, v1); acc8(a, v2); acc8(a, v3);
    }
    for (; i < cnt; i++) {
      uint4 v = *(const uint4*)(Hsq + (size_t)sh[ib + i] * 32);
      acc8(a, v);
    }
  } else {
    for (; i + 4 <= cnt; i += 4) {
      int s0 = srcs[beg + i], s1 = srcs[beg + i + 1], s2 = srcs[beg + i + 2], s3 = srcs[beg + i + 3];
      uint4 v0 = *(const uint4*)(Hsq + (size_t)s0 * 32);
      uint4 v1 = *(const uint4*)(Hsq + (size_t)s1 * 32);
      uint4 v2 = *(const uint4*)(Hsq + (size_t)s2 * 32);
      uint4 v3 = *(const uint4*)(Hsq + (size_t)s3 * 32);
      acc8(a, v0); acc8(a, v1); acc8(a, v2); acc8(a, v3);
    }
    for (; i < cnt; i++) {
      uint4 v = *(const uint4*)(Hsq + (size_t)srcs[beg + i] * 32);
      acc8(a, v);
    }
  }
  float dvn = dinv[n];
  f4 r0 = *(const f4*)(R + (size_t)n * 32 + q * 8);
  f4 r1 = *(const f4*)(R + (size_t)n * 32 + q * 8 + 4);
  float rr[8] = {r0.x, r0.y, r0.z, r0.w, r1.x, r1.y, r1.z, r1.w};
  float vv[8];
#pragma unroll
  for (int j = 0; j < 8; j++)
    vv[j] = fmaxf(a[j] * dvn + rr[j] + b1[q * 8 + j], 0.f);
  float pv[8];
#pragma unroll
  for (int j = 0; j < 8; j++) pv[j] = __shfl_xor(vv[j], 2);
  if (q < 2) {
    float hv[8];
#pragma unroll
    for (int j = 0; j < 8; j++) hv[j] = 0.5f * (vv[j] + pv[j]);
    f4 o0 = {hv[0], hv[1], hv[2], hv[3]};
    f4 o1 = {hv[4], hv[5], hv[6], hv[7]};
    *(f4*)(h + (size_t)n * 16 + q * 8) = o0;
    *(f4*)(h + (size_t)n * 16 + q * 8 + 4) = o1;
    uint4 ob;
    ob.x = bfpack(hv[0] * dvn, hv[1] * dvn);
    ob.y = bfpack(hv[2] * dvn, hv[3] * dvn);
    ob.z = bfpack(hv[4] * dvn, hv[5] * dvn);
    ob.w = bfpack(hv[6] * dvn, hv[7] * dvn);
    *(uint4*)(hs + (size_t)n * 16 + q * 8) = ob;
  }
}

// ---------------- prop2: Ah = dinv[n] * sum hs[src] ----------------
__global__ __launch_bounds__(TB) void k_prop2(const int* __restrict__ offsets,
                                              const int* __restrict__ degi,
                                              const int* __restrict__ srcs,
                                              const unsigned short* __restrict__ hs,
                                              const float* __restrict__ dinv,
                                              float* __restrict__ Ah, int N, int E) {
  __shared__ int sh[SCAP];
  int n0 = blockIdx.x * 64;
  int tid = threadIdx.x;
  int q = tid & 3;
  int n = n0 + (tid >> 2);
  int beg0 = offsets[n0];
  int end0 = (n0 + 64 < N) ? offsets[n0 + 64] : E;
  int seg = end0 - beg0;
  bool lds_ok = (seg <= SCAP);
  if (lds_ok) {
    for (int i = tid; i < seg; i += TB) sh[i] = srcs[beg0 + i];
  }
  __syncthreads();
  if (n >= N) return;
  int beg = offsets[n], cnt = degi[n];
  const unsigned short* hq = hs + q * 4;
  float a[4] = {0.f, 0.f, 0.f, 0.f};
  int i = 0;
  if (lds_ok) {
    int ib = beg - beg0;
    for (; i + 4 <= cnt; i += 4) {
      int s0 = sh[ib + i], s1 = sh[ib + i + 1], s2 = sh[ib + i + 2], s3 = sh[ib + i + 3];
      uint2 v0 = *(const uint2*)(hq + (size_t)s0 * 16);
      uint2 v1 = *(const uint2*)(hq + (size_t)s1 * 16);
      uint2 v2 = *(const uint2*)(hq + (size_t)s2 * 16);
      uint2 v3 = *(const uint2*)(hq + (size_t)s3 * 16);
      acc4(a, v0); acc4(a, v1); acc4(a, v2); acc4(a, v3);
    }
    for (; i < cnt; i++) {
      uint2 v = *(const uint2*)(hq + (size_t)sh[ib + i] * 16);
      acc4(a, v);
    }
  } else {
    for (; i + 4 <= cnt; i += 4) {
      int s0 = srcs[beg + i], s1 = srcs[beg + i + 1], s2 = srcs[beg + i + 2], s3 = srcs[beg + i + 3];
      uint2 v0 = *(const uint2*)(hq + (size_t)s0 * 16);
      uint2 v1 = *(const uint2*)(hq + (size_t)s1 * 16);
      uint2 v2 = *(const uint2*)(hq + (size_t)s2 * 16);
      uint2 v3 = *(const uint2*)(hq + (size_t)s3 * 16);
      acc4(a, v0); acc4(a, v1); acc4(a, v2); acc4(a, v3);
    }
    for (; i < cnt; i++) {
      uint2 v = *(const uint2*)(hq + (size_t)srcs[beg + i] * 16);
      acc4(a, v);
    }
  }
  float dvn = dinv[n];
  f4 o = {a[0] * dvn, a[1] * dvn, a[2] * dvn, a[3] * dvn};
  *(f4*)(Ah + (size_t)n * 16 + q * 4) = o;
}

// ---------------- final: out = mean_k relu(Ah@iw2_k + h@rw2_k + b2_k) --------
__global__ __launch_bounds__(TB) void k_final(const float* __restrict__ Ah,
                                              const float* __restrict__ h,
                                              const float* __restrict__ iw2,
                                              const float* __restrict__ rw2,
                                              const float* __restrict__ b2,
                                              float* __restrict__ out, int N) {
  __shared__ float w_iw[2 * 16 * 40];
  __shared__ float w_rw[2 * 16 * 40];
  __shared__ float w_b[2 * 40];
  for (int i = threadIdx.x; i < 1280; i += TB) {
    w_iw[i] = iw2[i];
    w_rw[i] = rw2[i];
  }
  for (int i = threadIdx.x; i < 80; i += TB) w_b[i] = b2[i];
  __syncthreads();

  int idx = blockIdx.x * TB + threadIdx.x;
  if (idx >= N * 40) return;
  int n = idx / 40;
  int o = idx - n * 40;
  float a[16], hr[16];
#pragma unroll
  for (int f = 0; f < 16; f++) {
    a[f] = Ah[(size_t)n * 16 + f];
    hr[f] = h[(size_t)n * 16 + f];
  }
  float res = 0.f;
#pragma unroll
  for (int k = 0; k < 2; k++) {
    float s = w_b[k * 40 + o];
#pragma unroll
    for (int f = 0; f < 16; f++) {
      s += a[f] * w_iw[(k * 16 + f) * 40 + o];
      s += hr[f] * w_rw[(k * 16 + f) * 40 + o];
    }
    res += fmaxf(s, 0.f);
  }
  out[idx] = 0.5f * res;
}

extern "C" void kernel_launch(void* const* d_in, const int* in_sizes, int n_in,
                              void* d_out, int out_size, void* d_ws, size_t ws_size,
                              hipStream_t stream) {
  const float* x = (const float*)d_in[0];
  const int* ei = (const int*)d_in[1];
  const float* iw1 = (const float*)d_in[2];
  const float* rw1 = (const float*)d_in[3];
  const float* b1 = (const float*)d_in[4];
  const float* iw2 = (const float*)d_in[5];
  const float* rw2 = (const float*)d_in[6];
  const float* b2 = (const float*)d_in[7];
  float* out = (float*)d_out;

  const int N = in_sizes[0] / 512;
  const int E = in_sizes[1] / 2;
  const int* src = ei;
  const int* dst = ei + E;
  const int NC = (N + 511) >> 9;  // coarse buckets (<=256 for N<=131072)

  char* base = (char*)d_ws;
  size_t off = 0;
  auto alloc = [&](size_t bytes) -> void* {
    off = (off + 255) & ~(size_t)255;
    void* p = base + off;
    off += bytes;
    return p;
  };
  int* degi = (int*)alloc((size_t)N * 4);
  float* dinv = (float*)alloc((size_t)N * 4);
  int* offsets = (int*)alloc((size_t)N * 4);
  int* cursor = (int*)alloc((size_t)N * 4);
  int* ccnt = (int*)alloc(260 * 4);
  int* cbase = (int*)alloc(260 * 4);
  int* ccur = (int*)alloc(260 * 4);
  unsigned int* epack = (unsigned int*)alloc((size_t)E * 4);
  int* srcs = (int*)alloc((size_t)E * 4);
  unsigned short* Hs = (unsigned short*)alloc((size_t)N * 32 * 2);
  float* R = (float*)alloc((size_t)N * 32 * 4);
  float* hbuf = (float*)alloc((size_t)N * 16 * 4);
  unsigned short* hs = (unsigned short*)alloc((size_t)N * 16 * 2);
  float* Ah = (float*)alloc((size_t)N * 16 * 4);
  short* Whi = (short*)alloc(32768 * 2);
  short* Wlo = (short*)alloc(32768 * 2);
  (void)ws_size;

  hipMemsetAsync(ccnt, 0, 260 * 4, stream);

  int NBLK = (E + CHA - 1) / CHA;
  int NPB = (N + 63) / 64;  // prop blocks (64 nodes each)
  k_countA<<<NBLK, TB, 0, stream>>>(dst, ccnt, E);
  k_scanC<<<1, 256, 0, stream>>>(ccnt, cbase, ccur);
  k_binA<<<NBLK, TB, 0, stream>>>(src, dst, ccur, epack, E);
  k_hist<<<NC, TB, 0, stream>>>(epack, cbase, degi, offsets, cursor, dinv, N);
  k_scat<<<dim3(NC, 8), TB, 0, stream>>>(epack, cbase, cursor, srcs);
  k_wsplit<<<128, TB, 0, stream>>>(iw1, rw1, Whi, Wlo);
  k_gemm1_mfma<<<(N + 63) / 64, TB, 0, stream>>>(x, Whi, Wlo, dinv, Hs, R, N);
  k_prop1<<<NPB, TB, 0, stream>>>(offsets, degi, srcs, Hs, R, dinv, b1, hbuf, hs, N, E);
  k_prop2<<<NPB, TB, 0, stream>>>(offsets, degi, srcs, hs, dinv, Ah, N, E);
  k_final<<<((size_t)N * 40 + TB - 1) / TB, TB, 0, stream>>>(Ah, hbuf, iw2, rw2, b2, out, N);
}